// Round 1
// baseline (51.937 us; speedup 1.0000x reference)
//
#include <hip/hip_runtime.h>
#include <hip/hip_bf16.h>
#include <float.h>

#define BB 128
#define SS 4096
#define TT 48
#define EE 10
#define RANGE 64   // steps per wave == wave size (used for zero-fill)

__device__ __forceinline__ int rfl(int x) { return __builtin_amdgcn_readfirstlane(x); }

// ---------------------------------------------------------------------------
// Kernel 1: parallel verified fast path.
// Each wave owns (b, t-range of 64). For each source step t it computes the
// emission-derived canonical state guess x and checks that the Viterbi argmax
// row into step t+1 is all-O (tag 0). Conservative per-lane test first; exact
// 48x48 recheck if it fails; per-b flag if even that fails. Output tags are 0
// everywhere except tags[S-1] = argmax_j(x_{S-1}[j] + end[j]).
// ---------------------------------------------------------------------------
__global__ __launch_bounds__(256) void k_fast(
    const int* __restrict__ tok_ids, const float* __restrict__ emb,
    const float* __restrict__ W, const float* __restrict__ bias,
    const float* __restrict__ start_t, const float* __restrict__ end_t,
    const float* __restrict__ trans, int* __restrict__ out,
    int* __restrict__ flags)
{
  __shared__ float xs[4][TT];
  const int lane  = threadIdx.x & 63;
  const int wslot = threadIdx.x >> 6;
  const int wid   = rfl(blockIdx.x * 4 + wslot);
  const int b  = wid >> 6;          // 64 ranges per batch row
  const int t0 = (wid & 63) << 6;   // * RANGE
  const int jj = lane < TT ? lane : TT - 1;

  // per-lane constants
  float w[EE];
#pragma unroll
  for (int d = 0; d < EE; ++d) w[d] = W[jj * EE + d];
  const float bj  = bias[jj];
  const float t0j = trans[0 * TT + jj];          // trans[0][j]
  const float bias_first = bj + start_t[jj];     // source step t==0
  const float bias_mix   = bj + t0j;             // source steps t>=1
  const float endj = end_t[jj];

  // conservative constant C = max_j( max_{i>=1} trans[i][j] - trans[0][j] ) + 0.5
  float tmax = -FLT_MAX;
#pragma unroll 1
  for (int i = 1; i < TT; ++i) tmax = fmaxf(tmax, trans[i * TT + jj]);
  float diff = (lane < TT) ? (tmax - t0j) : -FLT_MAX;
#pragma unroll
  for (int m = 32; m; m >>= 1) diff = fmaxf(diff, __shfl_xor(diff, m, 64));
  const float C = diff + 0.5f;

  // zero-fill this wave's 64-step output slice (skip the final slot: it gets
  // its own store below and same-wave store ordering to one address is unsafe)
  if (t0 + lane != SS - 1) out[b * SS + t0 + lane] = 0;

  // all 64 tokens of this range, one per lane (coalesced)
  const int toks = tok_ids[b * SS + t0 + lane];

  float x_last = 0.0f;
  for (int t = t0; t < t0 + RANGE; ++t) {
    const int tk = rfl(__builtin_amdgcn_readlane(toks, t - t0));
    const float* er = emb + (size_t)tk * EE;
    float x = (t == 0) ? bias_first : bias_mix;
#pragma unroll
    for (int d = 0; d < EE; ++d) x = fmaf(er[d], w[d], x);
    const float x0 = __shfl(x, 0, 64);
    if (t < SS - 1) {
      const bool pred = (lane == 0 || lane >= TT) ? true : (x + C <= x0);
      if (!__all(pred)) {
        // exact 48x48 argmax-row check (cold path)
        if (lane < TT) xs[wslot][lane] = x;
        __asm__ volatile("s_waitcnt lgkmcnt(0)" ::: "memory");
        float mx = -FLT_MAX;
        for (int i = 1; i < TT; ++i) mx = fmaxf(mx, xs[wslot][i] + trans[i * TT + jj]);
        const bool ok = (lane >= TT) ? true : (mx <= x0 + t0j - 0.25f);
        if (!__all(ok)) { if (lane == 0) atomicOr(&flags[b], 1); }
      }
    } else {
      x_last = x;
    }
  }

  if (t0 + RANGE == SS) {
    // tags[S-1] = argmax_j( x_{S-1}[j] + end[j] ), ties -> lowest j
    const float y = x_last + endj;
    if (lane < TT) xs[wslot][lane] = y;
    __asm__ volatile("s_waitcnt lgkmcnt(0)" ::: "memory");
    if (lane == 0) {
      float best = xs[wslot][0]; int bi = 0;
      for (int i = 1; i < TT; ++i) { float v = xs[wslot][i]; if (v > best) { best = v; bi = i; } }
      out[b * SS + (SS - 1)] = bi;
    }
  }
}

// ---------------------------------------------------------------------------
// Kernel 2: exact sequential fallback per batch row, runs only if flagged.
// Full Viterbi forward (bp bytes into d_ws) + backtrack, reference semantics:
// v = (score[i] + trans[i][j]) + em[j], strict > (ties -> lowest i).
// ---------------------------------------------------------------------------
__global__ __launch_bounds__(64) void k_fallback(
    const int* __restrict__ tok_ids, const float* __restrict__ emb,
    const float* __restrict__ W, const float* __restrict__ bias,
    const float* __restrict__ start_t, const float* __restrict__ end_t,
    const float* __restrict__ trans, int* __restrict__ out,
    const int* __restrict__ flags, unsigned char* __restrict__ bp)
{
  const int b = blockIdx.x;
  if (flags[b] == 0) return;

  __shared__ float sc[2][TT];
  const int lane = threadIdx.x;
  const int jj = lane < TT ? lane : TT - 1;
  float w[EE];
#pragma unroll
  for (int d = 0; d < EE; ++d) w[d] = W[jj * EE + d];
  const float bj = bias[jj];
  float tcol[TT];
#pragma unroll 1
  for (int i = 0; i < TT; ++i) tcol[i] = trans[i * TT + jj];

  {
    const int tk = tok_ids[b * SS + 0];
    const float* er = emb + (size_t)tk * EE;
    float em = bj;
#pragma unroll
    for (int d = 0; d < EE; ++d) em = fmaf(er[d], w[d], em);
    const float s0 = start_t[jj] + em;
    if (lane < TT) sc[0][lane] = s0;
  }
  __syncthreads();

  for (int t = 1; t < SS; ++t) {
    const int cur = (t - 1) & 1, nxt = t & 1;
    const int tk = tok_ids[b * SS + t];
    const float* er = emb + (size_t)tk * EE;
    float em = bj;
#pragma unroll
    for (int d = 0; d < EE; ++d) em = fmaf(er[d], w[d], em);
    float best = -FLT_MAX; int bpi = 0;
#pragma unroll 1
    for (int i = 0; i < TT; ++i) {
      const float v = (sc[cur][i] + tcol[i]) + em;
      if (v > best) { best = v; bpi = i; }
    }
    if (lane < TT) {
      bp[((size_t)(t - 1) * BB + b) * TT + lane] = (unsigned char)bpi;
      sc[nxt][lane] = best;
    }
    __syncthreads();
  }

  // final scores + argmax (S-1 is odd -> live buffer is sc[1]; stash into sc[0])
  if (lane < TT) sc[0][lane] = sc[1][lane] + end_t[jj];
  __syncthreads();
  if (lane == 0) {
    float best = sc[0][0]; int bi = 0;
    for (int i = 1; i < TT; ++i) { float v = sc[0][i]; if (v > best) { best = v; bi = i; } }
    int curtag = bi;
    out[b * SS + (SS - 1)] = curtag;
    for (int t = SS - 2; t >= 0; --t) {
      curtag = bp[((size_t)t * BB + b) * TT + curtag];
      out[b * SS + t] = curtag;
    }
  }
}

extern "C" void kernel_launch(void* const* d_in, const int* in_sizes, int n_in,
                              void* d_out, int out_size, void* d_ws, size_t ws_size,
                              hipStream_t stream) {
  const int*   tok_ids = (const int*)d_in[0];
  const float* emb     = (const float*)d_in[1];
  const float* W       = (const float*)d_in[2];
  const float* bias    = (const float*)d_in[3];
  const float* start_t = (const float*)d_in[4];
  const float* end_t   = (const float*)d_in[5];
  const float* trans   = (const float*)d_in[6];
  int* out = (int*)d_out;

  int* flags = (int*)d_ws;                                   // 128 ints
  unsigned char* bp = (unsigned char*)d_ws + 1024;           // fallback backpointers

  hipMemsetAsync(d_ws, 0, 512, stream);                      // clear flags each call

  // 128 b * 64 ranges = 8192 waves, 4 waves/block -> 2048 blocks
  k_fast<<<2048, 256, 0, stream>>>(tok_ids, emb, W, bias, start_t, end_t, trans,
                                   out, flags);
  k_fallback<<<BB, 64, 0, stream>>>(tok_ids, emb, W, bias, start_t, end_t, trans,
                                    out, flags, bp);
}

// Round 2
// 29.125 us; speedup vs baseline: 1.7833x; 1.7833x over previous
//
#include <hip/hip_runtime.h>
#include <hip/hip_bf16.h>
#include <float.h>

#define BB 128
#define SS 4096
#define TT 48
#define EE 10

__device__ __forceinline__ int rfl(int x) { return __builtin_amdgcn_readfirstlane(x); }

// ---------------------------------------------------------------------------
// ws layout:
//   [0      .. 511 ]  int flags[128]      (cleared by k_prep each call)
//   [512    .. 515 ]  float C             (cheap-test constant, written by k_prep)
//   [1024   .. +vocab] unsigned char safe[vocab]
//   [65536  .. ]      fallback backpointers (only touched if a row is flagged)
// ---------------------------------------------------------------------------

// Kernel P: clear flags + compute conservative constant
//   C = max_j( max_{i>=1} trans[i][j] - trans[0][j] ) + 0.5
__global__ __launch_bounds__(128) void k_prep(const float* __restrict__ trans,
                                              float* __restrict__ Cout,
                                              int* __restrict__ flags) {
  const int tid = threadIdx.x;
  flags[tid] = 0;  // blockDim == 128 == BB
  if (tid < 64) {
    const int lane = tid;
    const int jj = lane < TT ? lane : TT - 1;
    const float t0j = trans[jj];
    float tmax = -FLT_MAX;
#pragma unroll 1
    for (int i = 1; i < TT; ++i) tmax = fmaxf(tmax, trans[i * TT + jj]);
    float diff = (lane < TT) ? (tmax - t0j) : -FLT_MAX;
#pragma unroll
    for (int m = 32; m; m >>= 1) diff = fmaxf(diff, __shfl_xor(diff, m, 64));
    if (lane == 0) *Cout = diff + 0.5f;
  }
}

// Kernel V: one wave per vocab token. safe[tok] = 1 iff the Viterbi argmax
// row out of canonical state x (x_j = em_j + b_j + trans[0][j]) is all-O.
// Cheap per-lane test first; exact 48x48 check on the cold path.
__global__ __launch_bounds__(256) void k_vocab(
    const float* __restrict__ emb, const float* __restrict__ W,
    const float* __restrict__ bias, const float* __restrict__ trans,
    const float* __restrict__ Cp, unsigned char* __restrict__ safe, int vocab)
{
  const int lane = threadIdx.x & 63;
  const int tok = rfl(blockIdx.x * 4 + (threadIdx.x >> 6));
  if (tok >= vocab) return;
  const int jj = lane < TT ? lane : TT - 1;

  const float t0j = trans[jj];
  float x = bias[jj] + t0j;  // bias_mix
  const float* er = emb + (size_t)tok * EE;
#pragma unroll
  for (int d = 0; d < EE; ++d) x = fmaf(er[d], W[jj * EE + d], x);
  const float x0 = __shfl(x, 0, 64);
  const float C = *Cp;

  const bool pred = (lane == 0 || lane >= TT) ? true : (x + C <= x0);
  int s;
  if (__all(pred)) {
    s = 1;
  } else {
    float mx = -FLT_MAX;
#pragma unroll 1
    for (int i = 1; i < TT; ++i)
      mx = fmaxf(mx, __shfl(x, i, 64) + trans[i * TT + jj]);
    const bool ok = (lane >= TT) ? true : (mx <= x0 + t0j - 0.25f);
    s = __all(ok) ? 1 : 0;
  }
  if (lane == 0) safe[tok] = (unsigned char)s;
}

// Kernel B: 4 positions per thread. Zero-fill output, gather safe bits,
// flag the batch row on any unsafe interior token.
__global__ __launch_bounds__(256) void k_body(
    const int* __restrict__ tok_ids, const unsigned char* __restrict__ safe,
    int* __restrict__ out, int* __restrict__ flags)
{
  const int i = blockIdx.x * 256 + threadIdx.x;   // 131072 threads
  const int4 tk = ((const int4*)tok_ids)[i];
  ((int4*)out)[i] = make_int4(0, 0, 0, 0);
  const int base = i << 2;
  const int t = base & (SS - 1);
  bool fail = false;
  if (t != 0 && !safe[tk.x]) fail = true;          // t==0 handled in k_tail
  if (!safe[tk.y]) fail = true;                    // always interior
  if (!safe[tk.z]) fail = true;
  if (t + 3 != SS - 1 && !safe[tk.w]) fail = true; // S-1 has no outgoing check
  if (fail) atomicOr(&flags[base >> 12], 1);
}

// Kernel T: one wave per batch row. (1) exact t=0 check (start bias);
// (2) if row unflagged: final tag = argmax_j(x_{S-1}[j] + end[j]);
// (3) else: full sequential reference Viterbi (exact fallback).
__global__ __launch_bounds__(64) void k_tail(
    const int* __restrict__ tok_ids, const float* __restrict__ emb,
    const float* __restrict__ W, const float* __restrict__ bias,
    const float* __restrict__ start_t, const float* __restrict__ end_t,
    const float* __restrict__ trans, int* __restrict__ out,
    const int* __restrict__ flags, unsigned char* __restrict__ bp)
{
  const int b = blockIdx.x;
  const int lane = threadIdx.x;
  const int jj = lane < TT ? lane : TT - 1;
  float w[EE];
#pragma unroll
  for (int d = 0; d < EE; ++d) w[d] = W[jj * EE + d];
  const float bj = bias[jj];
  const float t0j = trans[jj];

  // ---- t=0 exact check (x uses start bias) ----
  {
    const int tk0 = tok_ids[b * SS];
    float x = bj + start_t[jj];
    const float* er = emb + (size_t)tk0 * EE;
#pragma unroll
    for (int d = 0; d < EE; ++d) x = fmaf(er[d], w[d], x);
    const float x0 = __shfl(x, 0, 64);
    float mx = -FLT_MAX;
#pragma unroll 1
    for (int i = 1; i < TT; ++i)
      mx = fmaxf(mx, __shfl(x, i, 64) + trans[i * TT + jj]);
    const bool ok = (lane >= TT) ? true : (mx <= x0 + t0j - 0.25f);
    const int flag = flags[b] | (__all(ok) ? 0 : 1);

    if (!flag) {
      // ---- fast final tag: argmax_j( em + b + trans[0][j] + end[j] ) ----
      const int tkL = tok_ids[b * SS + SS - 1];
      float y = bj + t0j + end_t[jj];
      const float* erL = emb + (size_t)tkL * EE;
#pragma unroll
      for (int d = 0; d < EE; ++d) y = fmaf(erL[d], w[d], y);
      if (lane >= TT) y = -FLT_MAX;
      int idx = lane;
#pragma unroll
      for (int m = 32; m; m >>= 1) {
        const float oy = __shfl_xor(y, m, 64);
        const int oi = __shfl_xor(idx, m, 64);
        if (oy > y || (oy == y && oi < idx)) { y = oy; idx = oi; }
      }
      if (lane == 0) out[b * SS + (SS - 1)] = idx;
      return;
    }
  }

  // ---- exact sequential fallback (reference semantics) ----
  __shared__ float sc[2][TT];
  float tcol[TT];
#pragma unroll 1
  for (int i = 0; i < TT; ++i) tcol[i] = trans[i * TT + jj];

  {
    const int tk = tok_ids[b * SS + 0];
    const float* er = emb + (size_t)tk * EE;
    float em = bj;
#pragma unroll
    for (int d = 0; d < EE; ++d) em = fmaf(er[d], w[d], em);
    if (lane < TT) sc[0][lane] = start_t[jj] + em;
  }
  __syncthreads();

  for (int t = 1; t < SS; ++t) {
    const int cur = (t - 1) & 1, nxt = t & 1;
    const int tk = tok_ids[b * SS + t];
    const float* er = emb + (size_t)tk * EE;
    float em = bj;
#pragma unroll
    for (int d = 0; d < EE; ++d) em = fmaf(er[d], w[d], em);
    float best = -FLT_MAX; int bpi = 0;
#pragma unroll 1
    for (int i = 0; i < TT; ++i) {
      const float v = (sc[cur][i] + tcol[i]) + em;
      if (v > best) { best = v; bpi = i; }
    }
    if (lane < TT) {
      bp[((size_t)(t - 1) * BB + b) * TT + lane] = (unsigned char)bpi;
      sc[nxt][lane] = best;
    }
    __syncthreads();
  }

  if (lane < TT) sc[0][lane] = sc[1][lane] + end_t[jj];
  __syncthreads();
  if (lane == 0) {
    float best = sc[0][0]; int bi = 0;
    for (int i = 1; i < TT; ++i) { float v = sc[0][i]; if (v > best) { best = v; bi = i; } }
    int curtag = bi;
    out[b * SS + (SS - 1)] = curtag;
    for (int t = SS - 2; t >= 0; --t) {
      curtag = bp[((size_t)t * BB + b) * TT + curtag];
      out[b * SS + t] = curtag;
    }
  }
}

extern "C" void kernel_launch(void* const* d_in, const int* in_sizes, int n_in,
                              void* d_out, int out_size, void* d_ws, size_t ws_size,
                              hipStream_t stream) {
  const int*   tok_ids = (const int*)d_in[0];
  const float* emb     = (const float*)d_in[1];
  const float* W       = (const float*)d_in[2];
  const float* bias    = (const float*)d_in[3];
  const float* start_t = (const float*)d_in[4];
  const float* end_t   = (const float*)d_in[5];
  const float* trans   = (const float*)d_in[6];
  int* out = (int*)d_out;

  const int vocab = in_sizes[1] / EE;

  int*           flags = (int*)d_ws;
  float*         Cp    = (float*)((char*)d_ws + 512);
  unsigned char* safe  = (unsigned char*)d_ws + 1024;
  unsigned char* bp    = (unsigned char*)d_ws + 65536;

  k_prep<<<1, 128, 0, stream>>>(trans, Cp, flags);
  k_vocab<<<(vocab + 3) / 4, 256, 0, stream>>>(emb, W, bias, trans, Cp, safe, vocab);
  k_body<<<(BB * SS / 4) / 256, 256, 0, stream>>>(tok_ids, safe, out, flags);
  k_tail<<<BB, 64, 0, stream>>>(tok_ids, emb, W, bias, start_t, end_t, trans,
                                out, flags, bp);
}